// Round 11
// baseline (3793.801 us; speedup 1.0000x reference)
//
#include <hip/hip_runtime.h>

// GridCellRouter: N=4096*4096 cells, 16 iterations of
//   accum[idx[i]] += cur[i];  cur[i] = accum[i] - cur[i]
//
// Recurrence (verified R4): c_{t+1} = S c_t + c_{t-1}, answer = c16 + c15.
// BSGS (verified R8): answer = sum_{k=0..16} alpha_k S^k r,
//   alpha = [1,8,36,84,210,252,462,330,495,220,286,78,91,14,15,1,1].
//   3 applies of S + 4 applies of T=S^4 (Horner, w_q fused into acc epilogue).
//
// Measured invariant (5 kernels): ANY pass touching 16.7M random cache lines
// costs ~320 us (b3 413, gather-apply 353, compose 317, cursor-route 316 with
// WRITE=510MB — L2-write-combining FALSIFIED). Fix: line-granular scatter
// staged IN LDS before leaving the CU:
//   lg_route: ONE-WAVE wgs (64 thr). Per 64-edge batch, claim-round loop:
//     one winner per bucket per round deposits into a 4-slot LDS staging
//     buffer; slot 3 triggers an ALIGNED 32B flush (2xuint4). No wraparound
//     hazard by construction; barriers only at wave-uniform points. Offsets
//     padded to 4-record multiples; tails zero-padded with (0,0) records
//     (acc adds 0.0 to acc[0]: harmless).
//   acc_op: sequential record read, LDS float atomics, fused w_q epilogue.
// Compose stays the PROVEN naive gather (3-phase compose regressed in R9).
// R17 = R10 + s2_scan BUGFIX: g_S[NBKT] must be run + v.w (was missing the
// last bucket's padded count -> bucket 1023 would read an empty range and
// produce zeros). Caught in pre-submit audit; R10 never executed (infra).
// Record array 2^25 slots; every flush address masked -> no OOB anywhere.

#define N_CELLS (1 << 24)

#define BKT_BITS 14
#define NBKT (N_CELLS >> BKT_BITS)        // 1024 buckets
#define DPB (1 << BKT_BITS)               // 16384 dsts per bucket
#define BKT_MASK (DPB - 1)
#define IDX_MASK (N_CELLS - 1)

#define NW 1024                           // route/count wgs (1 wave each)
#define EPW (N_CELLS / NW)                // 16384 edges per wg
#define RECN (1u << 25)                   // padded record space (33.5M slots)
#define REC_MASK (RECN - 1u)

typedef unsigned uv4 __attribute__((ext_vector_type(4)));
typedef float fv4 __attribute__((ext_vector_type(4)));
typedef unsigned long long u64;

__device__ __align__(16) unsigned g_T[2][NBKT * NW];       // (bucket,wg) offsets (padded)
__device__ __align__(16) unsigned g_bktcnt[2][NBKT];       // padded bucket totals
__device__ __align__(16) unsigned g_S[2][NBKT + 4];        // padded bucket starts
__device__ __align__(16) uint2 g_rec[RECN];                // records (val,dst14), 256MB
__device__ __align__(16) int g_idx2[N_CELLS];              // idx o idx
__device__ __align__(16) int g_idx4[N_CELLS];              // idx2 o idx2
__device__ __align__(16) float gB1[N_CELLS];               // S r
__device__ __align__(16) float gB2[N_CELLS];               // S^2 r
__device__ __align__(16) float gB3[N_CELLS];               // S^3 r
__device__ __align__(16) float gH[N_CELLS];                // Horner ping buffer

__device__ __forceinline__ unsigned pad4(unsigned c) { return (c + 3u) & ~3u; }

// compose (PROVEN naive): mode 0: idx2[i]=ext[ext[i]]; mode 1: idx4[i]=idx2[idx2[i]]
__global__ void compose_idx(const int* __restrict__ ext, int mode) {
    const int* __restrict__ a = mode ? g_idx2 : ext;
    int* __restrict__ o = mode ? g_idx4 : g_idx2;
    int i = (blockIdx.x * 256 + threadIdx.x) * 4;
    int4 v = *reinterpret_cast<const int4*>(a + i);
    int4 r;
    r.x = a[v.x & IDX_MASK];
    r.y = a[v.y & IDX_MASK];
    r.z = a[v.z & IDX_MASK];
    r.w = a[v.w & IDX_MASK];
    *reinterpret_cast<int4*>(o + i) = r;
}

// b1: raw counts per (bucket, wg). 1-wave wgs, NW of them.
__global__ void __launch_bounds__(64) b1_count(const int* __restrict__ ext, int set) {
    const int* __restrict__ idx = set ? g_idx4 : ext;
    __shared__ unsigned h[NBKT];
    int t = threadIdx.x;
    for (int b = t; b < NBKT; b += 64) h[b] = 0u;
    __syncthreads();
    const uv4* p = reinterpret_cast<const uv4*>(idx) + (size_t)blockIdx.x * (EPW / 4);
    for (int k = 0; k < EPW / 4 / 64; ++k) {   // 64 iters
        uv4 v = __builtin_nontemporal_load(&p[k * 64 + t]);
        atomicAdd(&h[(v.x & IDX_MASK) >> BKT_BITS], 1u);
        atomicAdd(&h[(v.y & IDX_MASK) >> BKT_BITS], 1u);
        atomicAdd(&h[(v.z & IDX_MASK) >> BKT_BITS], 1u);
        atomicAdd(&h[(v.w & IDX_MASK) >> BKT_BITS], 1u);
    }
    __syncthreads();
    for (int b = t; b < NBKT; b += 64) g_T[set][(size_t)b * NW + blockIdx.x] = h[b];
}

// s1: PADDED bucket totals (row of NW=1024 contiguous)
__global__ void s1_sums(int set) {
    __shared__ unsigned sd[256];
    int t = threadIdx.x;
    uint4 v = reinterpret_cast<const uint4*>(g_T[set] + (size_t)blockIdx.x * NW)[t];
    sd[t] = pad4(v.x) + pad4(v.y) + pad4(v.z) + pad4(v.w);
    __syncthreads();
    for (int off = 128; off > 0; off >>= 1) {
        if (t < off) sd[t] += sd[t + off];
        __syncthreads();
    }
    if (t == 0) g_bktcnt[set][blockIdx.x] = sd[0];
}

// s2: exclusive scan of padded bucket totals -> g_S; grand total at g_S[NBKT]
__global__ void s2_scan(int set) {
    __shared__ unsigned s[256];
    int t = threadIdx.x;
    uint4 v = reinterpret_cast<const uint4*>(g_bktcnt[set])[t];
    unsigned local = v.x + v.y + v.z + v.w;
    s[t] = local;
    __syncthreads();
    for (int off = 1; off < 256; off <<= 1) {
        unsigned add = (t >= off) ? s[t - off] : 0u;
        __syncthreads();
        s[t] += add;
        __syncthreads();
    }
    unsigned run = s[t] - local;
    uint4 o;
    o.x = run; run += v.x;
    o.y = run; run += v.y;
    o.z = run; run += v.z;
    o.w = run;
    reinterpret_cast<uint4*>(g_S[set])[t] = o;
    if (t == 255) g_S[set][NBKT] = run + v.w;   // BUGFIX: include last bucket
}

// s3: per-bucket exclusive scan of NW padded counts + base -> g_T = offsets
__global__ void __launch_bounds__(1024) s3_offsets(int set) {
    __shared__ unsigned s[NW];
    int t = threadIdx.x;
    unsigned c = pad4(g_T[set][(size_t)blockIdx.x * NW + t]);
    s[t] = c;
    __syncthreads();
    for (int off = 1; off < NW; off <<= 1) {
        unsigned add = (t >= off) ? s[t - off] : 0u;
        __syncthreads();
        s[t] += add;
        __syncthreads();
    }
    g_T[set][(size_t)blockIdx.x * NW + t] = g_S[set][blockIdx.x] + s[t] - c;
}

// pointer selector (host can't take addresses of __device__ statics)
__device__ __forceinline__ float* sel_buf(int which, const float* r, float* dout) {
    switch (which) {
        case 0: return (float*)r;
        case 1: return gB1;
        case 2: return gB2;
        case 3: return gB3;
        case 4: return gH;
        default: return dout;
    }
}

// lg_route: line-granular route. ONE wave per wg. Claim-round deposits into
// 4-slot/bucket LDS staging; aligned 32B flushes. Tail zero-padded.
__global__ void __launch_bounds__(64) lg_route(const float* __restrict__ rin,
                                               float* __restrict__ dout,
                                               const int* __restrict__ ext,
                                               int ct_sel, int set) {
    const int* __restrict__ idx = set ? g_idx4 : ext;
    const float* __restrict__ ct = sel_buf(ct_sel, rin, dout);
    __shared__ unsigned curA[NBKT];    // absolute record cursor (4KB)
    __shared__ unsigned claim[NBKT];   // per-round claims (4KB)
    __shared__ uint2 buf[NBKT][4];     // staging (32KB)
    int t = threadIdx.x;               // 0..63
    unsigned wg = blockIdx.x;
    for (int b = t; b < NBKT; b += 64) curA[b] = g_T[set][(size_t)b * NW + wg];
    __syncthreads();
    size_t ebase = (size_t)wg * EPW;
    for (int k = 0; k < EPW / 64; ++k) {   // 256 batches
        size_t e = ebase + (size_t)k * 64 + t;
        unsigned d = ((unsigned)__builtin_nontemporal_load(&idx[e])) & IDX_MASK;
        float v = __builtin_nontemporal_load(&ct[e]);
        unsigned b = d >> BKT_BITS;
        bool active = true;
        while (__any(active)) {
            if (active) claim[b] = (unsigned)t;
            __syncthreads();
            bool win = active && (claim[b] == (unsigned)t);
            if (win) {
                unsigned pos = curA[b];
                curA[b] = pos + 1u;
                unsigned slot = pos & 3u;
                buf[b][slot] = make_uint2(__float_as_uint(v), d & BKT_MASK);
                if (slot == 3u) {   // flush aligned 32B chunk
                    uint2 r0 = buf[b][0], r1 = buf[b][1];
                    uint2 r2 = buf[b][2], r3 = buf[b][3];
                    uint4* dst4 = reinterpret_cast<uint4*>(&g_rec[(pos - 3u) & REC_MASK]);
                    dst4[0] = make_uint4(r0.x, r0.y, r1.x, r1.y);
                    dst4[1] = make_uint4(r2.x, r2.y, r3.x, r3.y);
                }
                active = false;
            }
            __syncthreads();
        }
    }
    __syncthreads();
    // tail flush: zero-pad partial chunks to the 4-record boundary
    for (int b = t; b < NBKT; b += 64) {
        unsigned pos = curA[b];
        unsigned tl = pos & 3u;
        if (tl) {
            uint2 z = make_uint2(0u, 0u);
            uint2 r0 = buf[b][0];
            uint2 r1 = (tl > 1u) ? buf[b][1] : z;
            uint2 r2 = (tl > 2u) ? buf[b][2] : z;
            uint4* dst4 = reinterpret_cast<uint4*>(&g_rec[(pos - tl) & REC_MASK]);
            dst4[0] = make_uint4(r0.x, r0.y, r1.x, r1.y);
            dst4[1] = make_uint4(r2.x, r2.y, 0u, 0u);
        }
    }
}

// acc: sequential record read; LDS float-atomic acc over 16384 dsts;
// epilogue: out[row] = acc[row] + (fuse ? a0*r + a1*B1 + a2*B2 + a3*B3 : 0)
__global__ void __launch_bounds__(512) acc_op(const float* __restrict__ rin,
                                              float* __restrict__ dout,
                                              int out_sel, int set, int fuse,
                                              float a0, float a1, float a2, float a3) {
    __shared__ float acc[DPB];   // 64 KB
    int t = threadIdx.x;
    unsigned b = blockIdx.x;
    float* __restrict__ out = sel_buf(out_sel, rin, dout);
    unsigned base = g_S[set][b];
    unsigned end = g_S[set][b + 1];
    if (end > RECN) end = RECN;
    if (base > end) base = end;
    fv4* acc4 = reinterpret_cast<fv4*>(acc);
    fv4 z = (fv4)(0.0f);
    for (int k = 0; k < DPB / 4 / 512; ++k) acc4[k * 512 + t] = z;   // 8 iters
    __syncthreads();
    const u64* __restrict__ rec = reinterpret_cast<const u64*>(g_rec);
    unsigned e = base + t;
    for (; e + 1536 < end; e += 2048) {
        u64 q0 = __builtin_nontemporal_load(&rec[e]);
        u64 q1 = __builtin_nontemporal_load(&rec[e + 512]);
        u64 q2 = __builtin_nontemporal_load(&rec[e + 1024]);
        u64 q3 = __builtin_nontemporal_load(&rec[e + 1536]);
        atomicAdd(&acc[(unsigned)(q0 >> 32) & BKT_MASK], __uint_as_float((unsigned)q0));
        atomicAdd(&acc[(unsigned)(q1 >> 32) & BKT_MASK], __uint_as_float((unsigned)q1));
        atomicAdd(&acc[(unsigned)(q2 >> 32) & BKT_MASK], __uint_as_float((unsigned)q2));
        atomicAdd(&acc[(unsigned)(q3 >> 32) & BKT_MASK], __uint_as_float((unsigned)q3));
    }
    for (; e < end; e += 512) {
        u64 q = __builtin_nontemporal_load(&rec[e]);
        atomicAdd(&acc[(unsigned)(q >> 32) & BKT_MASK], __uint_as_float((unsigned)q));
    }
    __syncthreads();
    size_t rowbase = (size_t)b * (DPB / 4);
    fv4* out4 = reinterpret_cast<fv4*>(out) + rowbase;
    if (fuse) {
        const fv4* r4 = reinterpret_cast<const fv4*>(rin) + rowbase;
        const fv4* p1 = reinterpret_cast<const fv4*>(gB1) + rowbase;
        const fv4* p2 = reinterpret_cast<const fv4*>(gB2) + rowbase;
        const fv4* p3 = reinterpret_cast<const fv4*>(gB3) + rowbase;
        for (int k = 0; k < DPB / 4 / 512; ++k) {
            int j = k * 512 + t;
            fv4 a = acc4[j];
            fv4 x = __builtin_nontemporal_load(&r4[j]);
            fv4 y = __builtin_nontemporal_load(&p1[j]);
            fv4 u = __builtin_nontemporal_load(&p2[j]);
            fv4 w = __builtin_nontemporal_load(&p3[j]);
            a += a0 * x + a1 * y + a2 * u + a3 * w;
            __builtin_nontemporal_store(a, &out4[j]);
        }
    } else {
        for (int k = 0; k < DPB / 4 / 512; ++k) {
            int j = k * 512 + t;
            __builtin_nontemporal_store(acc4[j], &out4[j]);
        }
    }
}

extern "C" void kernel_launch(void* const* d_in, const int* in_sizes, int n_in,
                              void* d_out, int out_size, void* d_ws, size_t ws_size,
                              hipStream_t stream) {
    const int* idx = (const int*)d_in[1];
    const float* r = (const float*)d_in[0];   // read-only
    float* out = (float*)d_out;

    // ---- build S layout (set 0) ----
    b1_count<<<NW, 64, 0, stream>>>(idx, 0);
    s1_sums<<<NBKT, 256, 0, stream>>>(0);
    s2_scan<<<1, 256, 0, stream>>>(0);
    s3_offsets<<<NBKT, 1024, 0, stream>>>(0);

    // ---- idx4 = idx^4 (naive proven composes); build T layout (set 1) ----
    compose_idx<<<N_CELLS / 4 / 256, 256, 0, stream>>>(idx, 0);  // g_idx2
    compose_idx<<<N_CELLS / 4 / 256, 256, 0, stream>>>(idx, 1);  // g_idx4
    b1_count<<<NW, 64, 0, stream>>>(idx, 1);
    s1_sums<<<NBKT, 256, 0, stream>>>(1);
    s2_scan<<<1, 256, 0, stream>>>(1);
    s3_offsets<<<NBKT, 1024, 0, stream>>>(1);

    // ---- baby steps: B1 = S r, B2 = S B1, B3 = S B2 ----
    lg_route<<<NW, 64, 0, stream>>>(r, out, idx, 0, 0);
    acc_op<<<NBKT, 512, 0, stream>>>(r, out, 1, 0, 0, 0.f, 0.f, 0.f, 0.f);
    lg_route<<<NW, 64, 0, stream>>>(r, out, idx, 1, 0);
    acc_op<<<NBKT, 512, 0, stream>>>(r, out, 2, 0, 0, 0.f, 0.f, 0.f, 0.f);
    lg_route<<<NW, 64, 0, stream>>>(r, out, idx, 2, 0);
    acc_op<<<NBKT, 512, 0, stream>>>(r, out, 3, 0, 0, 0.f, 0.f, 0.f, 0.f);

    // ---- giant steps: Horner over T = S^4 ----
    // alpha (k=0..16): 1,8,36,84,210,252,462,330,495,220,286,78,91,14,15,1,1
    // g3 = T r  + w3 : (91,14,15,1)      -> gH
    lg_route<<<NW, 64, 0, stream>>>(r, out, idx, 0, 1);
    acc_op<<<NBKT, 512, 0, stream>>>(r, out, 4, 1, 1, 91.f, 14.f, 15.f, 1.f);
    // g2 = T g3 + w2 : (495,220,286,78)  -> d_out
    lg_route<<<NW, 64, 0, stream>>>(r, out, idx, 4, 1);
    acc_op<<<NBKT, 512, 0, stream>>>(r, out, 5, 1, 1, 495.f, 220.f, 286.f, 78.f);
    // g1 = T g2 + w1 : (210,252,462,330) -> gH
    lg_route<<<NW, 64, 0, stream>>>(r, out, idx, 5, 1);
    acc_op<<<NBKT, 512, 0, stream>>>(r, out, 4, 1, 1, 210.f, 252.f, 462.f, 330.f);
    // g0 = T g1 + w0 : (1,8,36,84)       -> d_out  (= answer)
    lg_route<<<NW, 64, 0, stream>>>(r, out, idx, 4, 1);
    acc_op<<<NBKT, 512, 0, stream>>>(r, out, 5, 1, 1, 1.f, 8.f, 36.f, 84.f);
}

// Round 13
// 3150.337 us; speedup vs baseline: 1.2043x; 1.2043x over previous
//
#include <hip/hip_runtime.h>

// GridCellRouter: N=4096*4096 cells, 16 iterations of
//   accum[idx[i]] += cur[i];  cur[i] = accum[i] - cur[i]
//
// Recurrence (verified R4): c_{t+1} = S c_t + c_{t-1}, answer = c16 + c15.
// BSGS (verified R8): answer = sum_{k=0..16} alpha_k S^k r,
//   alpha = [1,8,36,84,210,252,462,330,495,220,286,78,91,14,15,1,1].
//   3 applies of S + 4 applies of T=S^4 (Horner, w_q fused into acc epilogue).
//
// Measured invariant (6 variants): ANY pass touching ~16M random cache lines
// costs ~320 us, read or write; pass-internal engineering (LDS staging,
// claim rounds, 3-phase) does NOT break it (lg_route: WRITE 510->287 MB but
// 327 us, latency-bound at 11% occupancy -> REVERTED). 9 random passes
// (2 composes + 7 routes) => ~2880 us structural floor; R8 measured 3133.
//
// R12: the one untested lever — CO-SCHEDULE independent random passes.
// Each pass runs at only 15-45% of HBM peak (latency-bound, not a proven
// DRAM ceiling), so two co-resident passes should overlap. DAG pairs:
//   fat_cr #1: compose1 (idx2=idx.idx)   || route(S, r)     [16:1 interleave]
//   fat_cr #2: compose2 (idx4=idx2.idx2) || route(S, B1)
//   fat_br   : b1_count(T)               || route(S, B2)    [1:1 interleave]
// All components are R8-proven verbatim (plain route, unpadded records),
// re-gridded to 512 threads x 512 wgs. Falsifier: fat_cr ~630 us => shared
// random-access ceiling, overlap is a dead end.
// ALL indices masked/clamped -> no OOB possible anywhere.
// (R18 resubmit: R12 never ran — GPU broker timeout, no counters.)

#define N_CELLS (1 << 24)

#define BKT_BITS 14
#define NBKT (N_CELLS >> BKT_BITS)        // 1024 buckets
#define DPB (1 << BKT_BITS)               // 16384 dsts per bucket
#define BKT_MASK (DPB - 1)
#define IDX_MASK (N_CELLS - 1)
#define G1 512                            // route/count wgs
#define BT 512                            // threads everywhere (apply path)
#define EPW (N_CELLS / G1)                // 32768 edges per wg
#define CBLK 8192                         // compose blocks (512 thr x 4 elems)

typedef unsigned uv4 __attribute__((ext_vector_type(4)));
typedef float fv4 __attribute__((ext_vector_type(4)));
typedef unsigned long long u64;

__device__ __align__(16) unsigned g_T[2][NBKT * G1];       // (bucket,wg) offsets
__device__ __align__(16) unsigned g_bktcnt[2][NBKT];       // bucket totals
__device__ __align__(16) unsigned g_S[2][NBKT + 4];        // bucket starts (excl)
__device__ __align__(16) uint2 g_rec[N_CELLS];             // records (val,dst14)
__device__ __align__(16) int g_idx2[N_CELLS];              // idx o idx
__device__ __align__(16) int g_idx4[N_CELLS];              // idx2 o idx2
__device__ __align__(16) float gB1[N_CELLS];               // S r
__device__ __align__(16) float gB2[N_CELLS];               // S^2 r
__device__ __align__(16) float gB3[N_CELLS];               // S^3 r
__device__ __align__(16) float gH[N_CELLS];                // Horner ping buffer

// pointer selector (host can't take addresses of __device__ statics)
__device__ __forceinline__ float* sel_buf(int which, const float* r, float* dout) {
    switch (which) {
        case 0: return (float*)r;
        case 1: return gB1;
        case 2: return gB2;
        case 3: return gB3;
        case 4: return gH;
        default: return dout;
    }
}

// ---- device parts (shared by plain and fat kernels) ----

// compose element block: o[i] = a[a[i]] pattern (naive proven gather)
__device__ __forceinline__ void dev_compose(const int* __restrict__ ext, int mode,
                                            unsigned cid, int t) {
    const int* __restrict__ a = mode ? g_idx2 : ext;
    int* __restrict__ o = mode ? g_idx4 : g_idx2;
    size_t i = ((size_t)cid * BT + t) * 4;
    int4 v = *reinterpret_cast<const int4*>(a + i);
    int4 r;
    r.x = a[v.x & IDX_MASK];
    r.y = a[v.y & IDX_MASK];
    r.z = a[v.z & IDX_MASK];
    r.w = a[v.w & IDX_MASK];
    *reinterpret_cast<int4*>(o + i) = r;
}

// route wg: sequential NT reads of ct+idx chunk; scatter (val,dst14) records
// to per-(wg,bucket) runs via LDS cursors (R8-proven, re-gridded 512x512)
__device__ __forceinline__ void dev_route(const float* __restrict__ ct,
                                          const int* __restrict__ idx,
                                          unsigned* cur, unsigned wg, int t, int set) {
    cur[t] = g_T[set][(size_t)t * G1 + wg];
    cur[t + 512] = g_T[set][(size_t)(t + 512) * G1 + wg];
    __syncthreads();
    const uv4* ip = reinterpret_cast<const uv4*>(idx) + (size_t)wg * (EPW / 4);
    const fv4* cp = reinterpret_cast<const fv4*>(ct) + (size_t)wg * (EPW / 4);
    for (int k = 0; k < EPW / 4 / BT; ++k) {   // 16 iters
        uv4 v = __builtin_nontemporal_load(&ip[k * BT + t]);
        fv4 c = __builtin_nontemporal_load(&cp[k * BT + t]);
        unsigned e, p;
        e = v.x & IDX_MASK; p = atomicAdd(&cur[e >> BKT_BITS], 1u) & IDX_MASK;
        g_rec[p] = make_uint2(__float_as_uint(c.x), e & BKT_MASK);
        e = v.y & IDX_MASK; p = atomicAdd(&cur[e >> BKT_BITS], 1u) & IDX_MASK;
        g_rec[p] = make_uint2(__float_as_uint(c.y), e & BKT_MASK);
        e = v.z & IDX_MASK; p = atomicAdd(&cur[e >> BKT_BITS], 1u) & IDX_MASK;
        g_rec[p] = make_uint2(__float_as_uint(c.z), e & BKT_MASK);
        e = v.w & IDX_MASK; p = atomicAdd(&cur[e >> BKT_BITS], 1u) & IDX_MASK;
        g_rec[p] = make_uint2(__float_as_uint(c.w), e & BKT_MASK);
    }
}

// b1 wg: count edges per (bucket, wg)
__device__ __forceinline__ void dev_b1(const int* __restrict__ idx,
                                       unsigned* h, unsigned wg, int t, int set) {
    h[t] = 0u; h[t + 512] = 0u;
    __syncthreads();
    const uv4* p = reinterpret_cast<const uv4*>(idx) + (size_t)wg * (EPW / 4);
    for (int k = 0; k < EPW / 4 / BT; ++k) {   // 16 iters
        uv4 v = __builtin_nontemporal_load(&p[k * BT + t]);
        atomicAdd(&h[(v.x & IDX_MASK) >> BKT_BITS], 1u);
        atomicAdd(&h[(v.y & IDX_MASK) >> BKT_BITS], 1u);
        atomicAdd(&h[(v.z & IDX_MASK) >> BKT_BITS], 1u);
        atomicAdd(&h[(v.w & IDX_MASK) >> BKT_BITS], 1u);
    }
    __syncthreads();
    g_T[set][(size_t)t * G1 + wg] = h[t];
    g_T[set][(size_t)(t + 512) * G1 + wg] = h[t + 512];
}

// ---- plain kernels ----

__global__ void __launch_bounds__(BT) k_b1(const int* __restrict__ ext, int set) {
    __shared__ unsigned h[NBKT];
    const int* __restrict__ idx = set ? g_idx4 : ext;
    dev_b1(idx, h, blockIdx.x, threadIdx.x, set);
}

__global__ void __launch_bounds__(BT) k_route(const float* __restrict__ rin,
                                              float* __restrict__ dout,
                                              const int* __restrict__ ext,
                                              int ct_sel, int set) {
    __shared__ unsigned cur[NBKT];
    const int* __restrict__ idx = set ? g_idx4 : ext;
    const float* __restrict__ ct = sel_buf(ct_sel, rin, dout);
    dev_route(ct, idx, cur, blockIdx.x, threadIdx.x, set);
}

// fat: compose (16 of every 17 blocks) || route (1 of every 17)
__global__ void __launch_bounds__(BT) fat_cr(const float* __restrict__ rin,
                                             float* __restrict__ dout,
                                             const int* __restrict__ ext,
                                             int mode, int ct_sel, int set) {
    __shared__ unsigned cur[NBKT];
    unsigned b = blockIdx.x;
    unsigned q = b / 17u, rmd = b % 17u;
    if (rmd == 16u) {
        const int* __restrict__ idx = set ? g_idx4 : ext;
        const float* __restrict__ ct = sel_buf(ct_sel, rin, dout);
        dev_route(ct, idx, cur, q, threadIdx.x, set);
    } else {
        dev_compose(ext, mode, q * 16u + rmd, threadIdx.x);
    }
}

// fat: b1(T) (even blocks) || route (odd blocks)
__global__ void __launch_bounds__(BT) fat_br(const float* __restrict__ rin,
                                             float* __restrict__ dout,
                                             const int* __restrict__ ext,
                                             int ct_sel) {
    __shared__ unsigned lds[NBKT];
    unsigned b = blockIdx.x;
    if (b & 1u) {
        const float* __restrict__ ct = sel_buf(ct_sel, rin, dout);
        dev_route(ct, ext, lds, b >> 1, threadIdx.x, 0);   // route along S
    } else {
        dev_b1(g_idx4, lds, b >> 1, threadIdx.x, 1);       // count T edges
    }
}

// s1: bucket totals (row of G1=512 contiguous; 256 thr x uint2)
__global__ void s1_sums(int set) {
    __shared__ unsigned sd[256];
    int t = threadIdx.x;
    uint2 v = reinterpret_cast<const uint2*>(g_T[set] + (size_t)blockIdx.x * G1)[t];
    sd[t] = v.x + v.y;
    __syncthreads();
    for (int off = 128; off > 0; off >>= 1) {
        if (t < off) sd[t] += sd[t + off];
        __syncthreads();
    }
    if (t == 0) g_bktcnt[set][blockIdx.x] = sd[0];
}

// s2: exclusive scan of g_bktcnt[1024] -> g_S (R8-proven; totals sum to N)
__global__ void s2_scan(int set) {
    __shared__ unsigned s[256];
    int t = threadIdx.x;
    uint4 v = reinterpret_cast<const uint4*>(g_bktcnt[set])[t];
    unsigned local = v.x + v.y + v.z + v.w;
    s[t] = local;
    __syncthreads();
    for (int off = 1; off < 256; off <<= 1) {
        unsigned add = (t >= off) ? s[t - off] : 0u;
        __syncthreads();
        s[t] += add;
        __syncthreads();
    }
    unsigned run = s[t] - local;
    uint4 o;
    o.x = run; run += v.x;
    o.y = run; run += v.y;
    o.z = run; run += v.z;
    o.w = run;
    reinterpret_cast<uint4*>(g_S[set])[t] = o;
    if (t == 0) g_S[set][NBKT] = (unsigned)N_CELLS;
}

// s3: within-bucket exclusive scan of G1=512 wg counts + bucket base
__global__ void __launch_bounds__(BT) s3_offsets(int set) {
    __shared__ unsigned s[G1];
    int t = threadIdx.x;
    unsigned v = g_T[set][(size_t)blockIdx.x * G1 + t];
    s[t] = v;
    __syncthreads();
    for (int off = 1; off < G1; off <<= 1) {
        unsigned add = (t >= off) ? s[t - off] : 0u;
        __syncthreads();
        s[t] += add;
        __syncthreads();
    }
    g_T[set][(size_t)blockIdx.x * G1 + t] = g_S[set][blockIdx.x] + s[t] - v;
}

// acc: sequential record read; LDS float-atomic acc over 16384 dsts;
// epilogue: out[row] = acc[row] + (fuse ? a0*r + a1*B1 + a2*B2 + a3*B3 : 0)
__global__ void __launch_bounds__(512) acc_op(const float* __restrict__ rin,
                                              float* __restrict__ dout,
                                              int out_sel, int set, int fuse,
                                              float a0, float a1, float a2, float a3) {
    __shared__ float acc[DPB];   // 64 KB
    int t = threadIdx.x;
    unsigned b = blockIdx.x;
    float* __restrict__ out = sel_buf(out_sel, rin, dout);
    unsigned base = g_S[set][b];
    unsigned end = g_S[set][b + 1];
    if (end > (unsigned)N_CELLS) end = (unsigned)N_CELLS;
    if (base > end) base = end;
    fv4* acc4 = reinterpret_cast<fv4*>(acc);
    fv4 z = (fv4)(0.0f);
    for (int k = 0; k < DPB / 4 / 512; ++k) acc4[k * 512 + t] = z;   // 8 iters
    __syncthreads();
    const u64* __restrict__ rec = reinterpret_cast<const u64*>(g_rec);
    unsigned e = base + t;
    for (; e + 1536 < end; e += 2048) {
        u64 q0 = __builtin_nontemporal_load(&rec[e]);
        u64 q1 = __builtin_nontemporal_load(&rec[e + 512]);
        u64 q2 = __builtin_nontemporal_load(&rec[e + 1024]);
        u64 q3 = __builtin_nontemporal_load(&rec[e + 1536]);
        atomicAdd(&acc[(unsigned)(q0 >> 32) & BKT_MASK], __uint_as_float((unsigned)q0));
        atomicAdd(&acc[(unsigned)(q1 >> 32) & BKT_MASK], __uint_as_float((unsigned)q1));
        atomicAdd(&acc[(unsigned)(q2 >> 32) & BKT_MASK], __uint_as_float((unsigned)q2));
        atomicAdd(&acc[(unsigned)(q3 >> 32) & BKT_MASK], __uint_as_float((unsigned)q3));
    }
    for (; e < end; e += 512) {
        u64 q = __builtin_nontemporal_load(&rec[e]);
        atomicAdd(&acc[(unsigned)(q >> 32) & BKT_MASK], __uint_as_float((unsigned)q));
    }
    __syncthreads();
    size_t rowbase = (size_t)b * (DPB / 4);
    fv4* out4 = reinterpret_cast<fv4*>(out) + rowbase;
    if (fuse) {
        const fv4* r4 = reinterpret_cast<const fv4*>(rin) + rowbase;
        const fv4* p1 = reinterpret_cast<const fv4*>(gB1) + rowbase;
        const fv4* p2 = reinterpret_cast<const fv4*>(gB2) + rowbase;
        const fv4* p3 = reinterpret_cast<const fv4*>(gB3) + rowbase;
        for (int k = 0; k < DPB / 4 / 512; ++k) {
            int j = k * 512 + t;
            fv4 a = acc4[j];
            fv4 x = __builtin_nontemporal_load(&r4[j]);
            fv4 y = __builtin_nontemporal_load(&p1[j]);
            fv4 u = __builtin_nontemporal_load(&p2[j]);
            fv4 w = __builtin_nontemporal_load(&p3[j]);
            a += a0 * x + a1 * y + a2 * u + a3 * w;
            __builtin_nontemporal_store(a, &out4[j]);
        }
    } else {
        for (int k = 0; k < DPB / 4 / 512; ++k) {
            int j = k * 512 + t;
            __builtin_nontemporal_store(acc4[j], &out4[j]);
        }
    }
}

extern "C" void kernel_launch(void* const* d_in, const int* in_sizes, int n_in,
                              void* d_out, int out_size, void* d_ws, size_t ws_size,
                              hipStream_t stream) {
    const int* idx = (const int*)d_in[1];
    const float* r = (const float*)d_in[0];   // read-only
    float* out = (float*)d_out;

    // ---- build S layout (set 0) ----
    k_b1<<<G1, BT, 0, stream>>>(idx, 0);
    s1_sums<<<NBKT, 256, 0, stream>>>(0);
    s2_scan<<<1, 256, 0, stream>>>(0);
    s3_offsets<<<NBKT, BT, 0, stream>>>(0);

    // ---- overlapped phase ----
    // fat1: compose1 (idx2) || route(S, r)
    fat_cr<<<CBLK + G1, BT, 0, stream>>>(r, out, idx, 0, 0, 0);
    acc_op<<<NBKT, 512, 0, stream>>>(r, out, 1, 0, 0, 0.f, 0.f, 0.f, 0.f);   // B1
    // fat2: compose2 (idx4) || route(S, B1)
    fat_cr<<<CBLK + G1, BT, 0, stream>>>(r, out, idx, 1, 1, 0);
    acc_op<<<NBKT, 512, 0, stream>>>(r, out, 2, 0, 0, 0.f, 0.f, 0.f, 0.f);   // B2
    // fat3: b1(T) || route(S, B2)
    fat_br<<<2 * G1, BT, 0, stream>>>(r, out, idx, 2);
    acc_op<<<NBKT, 512, 0, stream>>>(r, out, 3, 0, 0, 0.f, 0.f, 0.f, 0.f);   // B3
    // T scans
    s1_sums<<<NBKT, 256, 0, stream>>>(1);
    s2_scan<<<1, 256, 0, stream>>>(1);
    s3_offsets<<<NBKT, BT, 0, stream>>>(1);

    // ---- giant steps: Horner over T = S^4 ----
    // alpha (k=0..16): 1,8,36,84,210,252,462,330,495,220,286,78,91,14,15,1,1
    // g3 = T r  + w3 : (91,14,15,1)      -> gH
    k_route<<<G1, BT, 0, stream>>>(r, out, idx, 0, 1);
    acc_op<<<NBKT, 512, 0, stream>>>(r, out, 4, 1, 1, 91.f, 14.f, 15.f, 1.f);
    // g2 = T g3 + w2 : (495,220,286,78)  -> d_out
    k_route<<<G1, BT, 0, stream>>>(r, out, idx, 4, 1);
    acc_op<<<NBKT, 512, 0, stream>>>(r, out, 5, 1, 1, 495.f, 220.f, 286.f, 78.f);
    // g1 = T g2 + w1 : (210,252,462,330) -> gH
    k_route<<<G1, BT, 0, stream>>>(r, out, idx, 5, 1);
    acc_op<<<NBKT, 512, 0, stream>>>(r, out, 4, 1, 1, 210.f, 252.f, 462.f, 330.f);
    // g0 = T g1 + w0 : (1,8,36,84)       -> d_out  (= answer)
    k_route<<<G1, BT, 0, stream>>>(r, out, idx, 4, 1);
    acc_op<<<NBKT, 512, 0, stream>>>(r, out, 5, 1, 1, 1.f, 8.f, 36.f, 84.f);
}

// Round 14
// 2579.361 us; speedup vs baseline: 1.4708x; 1.2214x over previous
//
#include <hip/hip_runtime.h>

// GridCellRouter: N=4096*4096 cells, 16 iterations of
//   accum[idx[i]] += cur[i];  cur[i] = accum[i] - cur[i]
//
// Recurrence (verified R4): c_{t+1} = S c_t + c_{t-1}, answer = c16 + c15.
// BSGS (verified R8): answer = sum_{k=0..16} alpha_k S^k r,
//   alpha = [1,8,36,84,210,252,462,330,495,220,286,78,91,14,15,1,1].
//   3 applies of S + 4 applies of T=S^4 (Horner, w_q fused into acc epilogue).
//
// Measured physics (R13): random-line passes are THROUGHPUT-bound at
// ~3-3.5 TB/s effective (fat_cr 3.0 TB/s ~ solo compose 3.5) — overlap
// recovers only 13%; 1024-cursor scatter thrashes L2 (510 MB writes).
// R14: two-level radix route. A 32-STREAM scatter is 32-way interleaved
// sequential (16 KB runs) — compact at DRAM:
//   route1: seq read idx+ct chunk; scatter (val,dst24) via 32 LDS cursors
//           into super-bucket-major g_tmp (super = dst>>19).
//   route2: one wg per (super, group-of-32-wg1s): seq read of FULL runs;
//           scatter via 32 sub-bucket cursors into final-bucket g_rec.
//   offsets: derived from b1's g_T[bucket][wg] by tiny kernels d_off1/d_off2
//           (no extra big passes). acc unchanged (g_S-based).
// Composes stay naive (proven 317 us). Falsifier: route1/route2 >= ~300 us
// => interleaved-stream scatter also hits the ~320 us invariant => roofline.
// ALL indices masked -> no OOB anywhere.

#define N_CELLS (1 << 24)

#define BKT_BITS 14
#define NBKT (N_CELLS >> BKT_BITS)        // 1024 final buckets
#define DPB (1 << BKT_BITS)               // 16384 dsts per bucket
#define BKT_MASK (DPB - 1)
#define IDX_MASK (N_CELLS - 1)
#define NSUP 32                           // super buckets (dst >> 19)
#define SUP_SHIFT 19
#define G1 256                            // b1/route1 wgs
#define BT 1024                           // threads in b1/route1/route2
#define EPW (N_CELLS / G1)                // 65536 edges per wg

typedef unsigned uv4 __attribute__((ext_vector_type(4)));
typedef float fv4 __attribute__((ext_vector_type(4)));
typedef unsigned long long u64;

__device__ __align__(16) unsigned g_T[2][NBKT * G1];      // b1 counts (bucket, wg)
__device__ __align__(16) unsigned g_bktcnt[2][NBKT];      // bucket totals
__device__ __align__(16) unsigned g_S[2][NBKT + 4];       // bucket starts (excl)
__device__ __align__(16) unsigned g_off1[2][NSUP * G1];   // route1 cursors (super, wg)
__device__ __align__(16) unsigned g_off2[2][NBKT * 8];    // route2 cursors (bucket, group)
__device__ __align__(16) uint2 g_tmp[N_CELLS];            // pass-1 records (val, dst24)
__device__ __align__(16) uint2 g_rec[N_CELLS];            // final records (val, dst)
__device__ __align__(16) int g_idx2[N_CELLS];             // idx o idx
__device__ __align__(16) int g_idx4[N_CELLS];             // idx2 o idx2
__device__ __align__(16) float gB1[N_CELLS];              // S r
__device__ __align__(16) float gB2[N_CELLS];              // S^2 r
__device__ __align__(16) float gB3[N_CELLS];              // S^3 r
__device__ __align__(16) float gH[N_CELLS];               // Horner ping buffer

// pointer selector (host can't take addresses of __device__ statics)
__device__ __forceinline__ float* sel_buf(int which, const float* r, float* dout) {
    switch (which) {
        case 0: return (float*)r;
        case 1: return gB1;
        case 2: return gB2;
        case 3: return gB3;
        case 4: return gH;
        default: return dout;
    }
}

// compose (proven naive): mode 0: idx2[i]=ext[ext[i]]; mode 1: idx4[i]=idx2[idx2[i]]
__global__ void compose_idx(const int* __restrict__ ext, int mode) {
    const int* __restrict__ a = mode ? g_idx2 : ext;
    int* __restrict__ o = mode ? g_idx4 : g_idx2;
    int i = (blockIdx.x * 256 + threadIdx.x) * 4;
    int4 v = *reinterpret_cast<const int4*>(a + i);
    int4 r;
    r.x = a[v.x & IDX_MASK];
    r.y = a[v.y & IDX_MASK];
    r.z = a[v.z & IDX_MASK];
    r.w = a[v.w & IDX_MASK];
    *reinterpret_cast<int4*>(o + i) = r;
}

// b1: count edges per (final bucket, wg). NBKT == BT == 1024.
__global__ void __launch_bounds__(BT) b1_count(const int* __restrict__ ext, int set) {
    const int* __restrict__ idx = set ? g_idx4 : ext;
    __shared__ unsigned h[NBKT];
    int t = threadIdx.x;
    h[t] = 0u;
    __syncthreads();
    const uv4* p = reinterpret_cast<const uv4*>(idx) + (size_t)blockIdx.x * (EPW / 4);
    for (int k = 0; k < EPW / 4 / BT; ++k) {   // 16 iters
        uv4 v = __builtin_nontemporal_load(&p[k * BT + t]);
        atomicAdd(&h[(v.x & IDX_MASK) >> BKT_BITS], 1u);
        atomicAdd(&h[(v.y & IDX_MASK) >> BKT_BITS], 1u);
        atomicAdd(&h[(v.z & IDX_MASK) >> BKT_BITS], 1u);
        atomicAdd(&h[(v.w & IDX_MASK) >> BKT_BITS], 1u);
    }
    __syncthreads();
    g_T[set][(size_t)t * G1 + blockIdx.x] = h[t];
}

// s1: bucket totals (row of G1=256 contiguous)
__global__ void s1_sums(int set) {
    __shared__ unsigned sd[256];
    int t = threadIdx.x;
    sd[t] = g_T[set][(size_t)blockIdx.x * G1 + t];
    __syncthreads();
    for (int off = 128; off > 0; off >>= 1) {
        if (t < off) sd[t] += sd[t + off];
        __syncthreads();
    }
    if (t == 0) g_bktcnt[set][blockIdx.x] = sd[0];
}

// s2: exclusive scan of g_bktcnt[1024] -> g_S (proven pattern; sums to N)
__global__ void s2_scan(int set) {
    __shared__ unsigned s[256];
    int t = threadIdx.x;
    uint4 v = reinterpret_cast<const uint4*>(g_bktcnt[set])[t];
    unsigned local = v.x + v.y + v.z + v.w;
    s[t] = local;
    __syncthreads();
    for (int off = 1; off < 256; off <<= 1) {
        unsigned add = (t >= off) ? s[t - off] : 0u;
        __syncthreads();
        s[t] += add;
        __syncthreads();
    }
    unsigned run = s[t] - local;
    uint4 o;
    o.x = run; run += v.x;
    o.y = run; run += v.y;
    o.z = run; run += v.z;
    o.w = run;
    reinterpret_cast<uint4*>(g_S[set])[t] = o;
    if (t == 0) g_S[set][NBKT] = (unsigned)N_CELLS;
}

// d_off1: route1 cursor bases. off1[s][w] = g_S[s*32] +
//   excl-prefix_w( sum_{b in super s} g_T[b][w] ). Grid: NSUP wgs x 256 thr.
__global__ void d_off1(int set) {
    __shared__ unsigned sc[G1];
    int w = threadIdx.x;
    unsigned s = blockIdx.x;
    unsigned c = 0u;
    for (int j = 0; j < NBKT / NSUP; ++j)   // 32 buckets per super
        c += g_T[set][(size_t)(s * (NBKT / NSUP) + j) * G1 + w];
    sc[w] = c;
    __syncthreads();
    for (int off = 1; off < G1; off <<= 1) {
        unsigned add = (w >= off) ? sc[w - off] : 0u;
        __syncthreads();
        sc[w] += add;
        __syncthreads();
    }
    g_off1[set][(size_t)s * G1 + w] = g_S[set][s * (NBKT / NSUP)] + sc[w] - c;
}

// d_off2: route2 cursor bases. off2[b][g] = g_S[b] +
//   sum_{g'<g} ( sum_{w in group g'} g_T[b][w] ). Grid: NBKT wgs x 256 thr.
__global__ void d_off2(int set) {
    __shared__ unsigned sd[256];
    int t = threadIdx.x;
    unsigned b = blockIdx.x;
    sd[t] = g_T[set][(size_t)b * G1 + t];
    __syncthreads();
    for (int off = 16; off > 0; off >>= 1) {   // reduce within each group of 32
        if ((t & 31) < off) sd[t] += sd[t + off];
        __syncthreads();
    }
    if (t == 0) {
        unsigned run = g_S[set][b];
        for (int g = 0; g < 8; ++g) {
            g_off2[set][(size_t)b * 8 + g] = run;
            run += sd[g * 32];
        }
    }
}

// route1: seq read idx+ct chunk; scatter (val, dst24) via 32 LDS cursors
// into super-bucket-major g_tmp. 16KB avg run per (super,wg) -> compact writes.
__global__ void __launch_bounds__(BT) route1(const float* __restrict__ rin,
                                             float* __restrict__ dout,
                                             const int* __restrict__ ext,
                                             int ct_sel, int set) {
    const int* __restrict__ idx = set ? g_idx4 : ext;
    const float* __restrict__ ct = sel_buf(ct_sel, rin, dout);
    __shared__ unsigned cur[NSUP];
    int t = threadIdx.x;
    if (t < NSUP) cur[t] = g_off1[set][(size_t)t * G1 + blockIdx.x];
    __syncthreads();
    const uv4* ip = reinterpret_cast<const uv4*>(idx) + (size_t)blockIdx.x * (EPW / 4);
    const fv4* cp = reinterpret_cast<const fv4*>(ct) + (size_t)blockIdx.x * (EPW / 4);
    for (int k = 0; k < EPW / 4 / BT; ++k) {   // 16 iters
        uv4 v = __builtin_nontemporal_load(&ip[k * BT + t]);
        fv4 c = __builtin_nontemporal_load(&cp[k * BT + t]);
        unsigned e, p;
        e = v.x & IDX_MASK; p = atomicAdd(&cur[e >> SUP_SHIFT], 1u) & IDX_MASK;
        g_tmp[p] = make_uint2(__float_as_uint(c.x), e);
        e = v.y & IDX_MASK; p = atomicAdd(&cur[e >> SUP_SHIFT], 1u) & IDX_MASK;
        g_tmp[p] = make_uint2(__float_as_uint(c.y), e);
        e = v.z & IDX_MASK; p = atomicAdd(&cur[e >> SUP_SHIFT], 1u) & IDX_MASK;
        g_tmp[p] = make_uint2(__float_as_uint(c.z), e);
        e = v.w & IDX_MASK; p = atomicAdd(&cur[e >> SUP_SHIFT], 1u) & IDX_MASK;
        g_tmp[p] = make_uint2(__float_as_uint(c.w), e);
    }
}

// route2: wg = (super s, group g of 32 wg1s). Seq read of the group's FULL
// runs in g_tmp; scatter via 32 sub-bucket cursors into final-bucket g_rec.
__global__ void __launch_bounds__(BT) route2(int set) {
    __shared__ unsigned cur[NSUP];
    unsigned wg = blockIdx.x;                 // 256
    unsigned s = wg >> 3, g = wg & 7u;
    int t = threadIdx.x;
    if (t < NSUP) cur[t] = g_off2[set][(size_t)(s * NSUP + t) * 8 + g];
    __syncthreads();
    unsigned start = g_off1[set][(size_t)s * G1 + g * 32];
    unsigned end = (g < 7u) ? g_off1[set][(size_t)s * G1 + (g + 1) * 32]
                            : g_S[set][(s + 1) * NSUP];
    if (start > end) start = end;
    const u64* __restrict__ tmp = reinterpret_cast<const u64*>(g_tmp);
    unsigned e = start + t;
    for (; e + 3 * BT < end; e += 4 * BT) {
        u64 q0 = __builtin_nontemporal_load(&tmp[e]);
        u64 q1 = __builtin_nontemporal_load(&tmp[e + BT]);
        u64 q2 = __builtin_nontemporal_load(&tmp[e + 2 * BT]);
        u64 q3 = __builtin_nontemporal_load(&tmp[e + 3 * BT]);
        unsigned d0 = (unsigned)(q0 >> 32), d1 = (unsigned)(q1 >> 32);
        unsigned d2 = (unsigned)(q2 >> 32), d3 = (unsigned)(q3 >> 32);
        unsigned p0 = atomicAdd(&cur[(d0 >> BKT_BITS) & 31u], 1u) & IDX_MASK;
        unsigned p1 = atomicAdd(&cur[(d1 >> BKT_BITS) & 31u], 1u) & IDX_MASK;
        unsigned p2 = atomicAdd(&cur[(d2 >> BKT_BITS) & 31u], 1u) & IDX_MASK;
        unsigned p3 = atomicAdd(&cur[(d3 >> BKT_BITS) & 31u], 1u) & IDX_MASK;
        g_rec[p0] = make_uint2((unsigned)q0, d0);
        g_rec[p1] = make_uint2((unsigned)q1, d1);
        g_rec[p2] = make_uint2((unsigned)q2, d2);
        g_rec[p3] = make_uint2((unsigned)q3, d3);
    }
    for (; e < end; e += BT) {
        u64 q = __builtin_nontemporal_load(&tmp[e]);
        unsigned d = (unsigned)(q >> 32);
        unsigned p = atomicAdd(&cur[(d >> BKT_BITS) & 31u], 1u) & IDX_MASK;
        g_rec[p] = make_uint2((unsigned)q, d);
    }
}

// acc: sequential record read; LDS float-atomic acc over 16384 dsts;
// epilogue: out[row] = acc[row] + (fuse ? a0*r + a1*B1 + a2*B2 + a3*B3 : 0)
__global__ void __launch_bounds__(512) acc_op(const float* __restrict__ rin,
                                              float* __restrict__ dout,
                                              int out_sel, int set, int fuse,
                                              float a0, float a1, float a2, float a3) {
    __shared__ float acc[DPB];   // 64 KB
    int t = threadIdx.x;
    unsigned b = blockIdx.x;
    float* __restrict__ out = sel_buf(out_sel, rin, dout);
    unsigned base = g_S[set][b];
    unsigned end = g_S[set][b + 1];
    if (end > (unsigned)N_CELLS) end = (unsigned)N_CELLS;
    if (base > end) base = end;
    fv4* acc4 = reinterpret_cast<fv4*>(acc);
    fv4 z = (fv4)(0.0f);
    for (int k = 0; k < DPB / 4 / 512; ++k) acc4[k * 512 + t] = z;   // 8 iters
    __syncthreads();
    const u64* __restrict__ rec = reinterpret_cast<const u64*>(g_rec);
    unsigned e = base + t;
    for (; e + 1536 < end; e += 2048) {
        u64 q0 = __builtin_nontemporal_load(&rec[e]);
        u64 q1 = __builtin_nontemporal_load(&rec[e + 512]);
        u64 q2 = __builtin_nontemporal_load(&rec[e + 1024]);
        u64 q3 = __builtin_nontemporal_load(&rec[e + 1536]);
        atomicAdd(&acc[(unsigned)(q0 >> 32) & BKT_MASK], __uint_as_float((unsigned)q0));
        atomicAdd(&acc[(unsigned)(q1 >> 32) & BKT_MASK], __uint_as_float((unsigned)q1));
        atomicAdd(&acc[(unsigned)(q2 >> 32) & BKT_MASK], __uint_as_float((unsigned)q2));
        atomicAdd(&acc[(unsigned)(q3 >> 32) & BKT_MASK], __uint_as_float((unsigned)q3));
    }
    for (; e < end; e += 512) {
        u64 q = __builtin_nontemporal_load(&rec[e]);
        atomicAdd(&acc[(unsigned)(q >> 32) & BKT_MASK], __uint_as_float((unsigned)q));
    }
    __syncthreads();
    size_t rowbase = (size_t)b * (DPB / 4);
    fv4* out4 = reinterpret_cast<fv4*>(out) + rowbase;
    if (fuse) {
        const fv4* r4 = reinterpret_cast<const fv4*>(rin) + rowbase;
        const fv4* p1 = reinterpret_cast<const fv4*>(gB1) + rowbase;
        const fv4* p2 = reinterpret_cast<const fv4*>(gB2) + rowbase;
        const fv4* p3 = reinterpret_cast<const fv4*>(gB3) + rowbase;
        for (int k = 0; k < DPB / 4 / 512; ++k) {
            int j = k * 512 + t;
            fv4 a = acc4[j];
            fv4 x = __builtin_nontemporal_load(&r4[j]);
            fv4 y = __builtin_nontemporal_load(&p1[j]);
            fv4 u = __builtin_nontemporal_load(&p2[j]);
            fv4 w = __builtin_nontemporal_load(&p3[j]);
            a += a0 * x + a1 * y + a2 * u + a3 * w;
            __builtin_nontemporal_store(a, &out4[j]);
        }
    } else {
        for (int k = 0; k < DPB / 4 / 512; ++k) {
            int j = k * 512 + t;
            __builtin_nontemporal_store(acc4[j], &out4[j]);
        }
    }
}

extern "C" void kernel_launch(void* const* d_in, const int* in_sizes, int n_in,
                              void* d_out, int out_size, void* d_ws, size_t ws_size,
                              hipStream_t stream) {
    const int* idx = (const int*)d_in[1];
    const float* r = (const float*)d_in[0];   // read-only
    float* out = (float*)d_out;

    // ---- build S layout (set 0) ----
    b1_count<<<G1, BT, 0, stream>>>(idx, 0);
    s1_sums<<<NBKT, 256, 0, stream>>>(0);
    s2_scan<<<1, 256, 0, stream>>>(0);
    d_off1<<<NSUP, G1, 0, stream>>>(0);
    d_off2<<<NBKT, 256, 0, stream>>>(0);

    // ---- idx4 = idx^4 (proven naive); build T layout (set 1) ----
    compose_idx<<<N_CELLS / 4 / 256, 256, 0, stream>>>(idx, 0);  // g_idx2
    compose_idx<<<N_CELLS / 4 / 256, 256, 0, stream>>>(idx, 1);  // g_idx4
    b1_count<<<G1, BT, 0, stream>>>(idx, 1);
    s1_sums<<<NBKT, 256, 0, stream>>>(1);
    s2_scan<<<1, 256, 0, stream>>>(1);
    d_off1<<<NSUP, G1, 0, stream>>>(1);
    d_off2<<<NBKT, 256, 0, stream>>>(1);

    // ---- baby steps: B1 = S r, B2 = S B1, B3 = S B2 ----
    route1<<<G1, BT, 0, stream>>>(r, out, idx, 0, 0);
    route2<<<G1, BT, 0, stream>>>(0);
    acc_op<<<NBKT, 512, 0, stream>>>(r, out, 1, 0, 0, 0.f, 0.f, 0.f, 0.f);
    route1<<<G1, BT, 0, stream>>>(r, out, idx, 1, 0);
    route2<<<G1, BT, 0, stream>>>(0);
    acc_op<<<NBKT, 512, 0, stream>>>(r, out, 2, 0, 0, 0.f, 0.f, 0.f, 0.f);
    route1<<<G1, BT, 0, stream>>>(r, out, idx, 2, 0);
    route2<<<G1, BT, 0, stream>>>(0);
    acc_op<<<NBKT, 512, 0, stream>>>(r, out, 3, 0, 0, 0.f, 0.f, 0.f, 0.f);

    // ---- giant steps: Horner over T = S^4 ----
    // alpha (k=0..16): 1,8,36,84,210,252,462,330,495,220,286,78,91,14,15,1,1
    // g3 = T r  + w3 : (91,14,15,1)      -> gH
    route1<<<G1, BT, 0, stream>>>(r, out, idx, 0, 1);
    route2<<<G1, BT, 0, stream>>>(1);
    acc_op<<<NBKT, 512, 0, stream>>>(r, out, 4, 1, 1, 91.f, 14.f, 15.f, 1.f);
    // g2 = T g3 + w2 : (495,220,286,78)  -> d_out
    route1<<<G1, BT, 0, stream>>>(r, out, idx, 4, 1);
    route2<<<G1, BT, 0, stream>>>(1);
    acc_op<<<NBKT, 512, 0, stream>>>(r, out, 5, 1, 1, 495.f, 220.f, 286.f, 78.f);
    // g1 = T g2 + w1 : (210,252,462,330) -> gH
    route1<<<G1, BT, 0, stream>>>(r, out, idx, 5, 1);
    route2<<<G1, BT, 0, stream>>>(1);
    acc_op<<<NBKT, 512, 0, stream>>>(r, out, 4, 1, 1, 210.f, 252.f, 462.f, 330.f);
    // g0 = T g1 + w0 : (1,8,36,84)       -> d_out  (= answer)
    route1<<<G1, BT, 0, stream>>>(r, out, idx, 4, 1);
    route2<<<G1, BT, 0, stream>>>(1);
    acc_op<<<NBKT, 512, 0, stream>>>(r, out, 5, 1, 1, 1.f, 8.f, 36.f, 84.f);
}